// Round 21
// baseline (47.710 us; speedup 1.0000x reference)
//
#include <hip/hip_runtime.h>
#include <math.h>

// CasperNet R21: B=131072, D=256, H=64, O=10.
// R16-R20 plateau (50.0/52.7/50.4/47.5/46.8us) with no pipe >23% ->
// structural latency. Unablated serializer: the mid-kernel __syncthreads
// (only needed because transpose patches aliased sW). It re-convoys all
// 8 waves at the phase-1/phase-2 boundary, so the MFMA/LDS-heavy phase 1
// and the trans/VALU-heavy solve never overlap across waves.
// R21: dedicated 10.2KB patch buffer (LDS 51.7->62.2KB, still 2 blocks/CU;
// the 3-block residency never materialized per occ ~41%) and DELETE the
// second barrier -> waves flow phase1->phase2 privately and heterogeneous
// phases overlap. Math bit-identical to R20.
// Layout (verified R5): MFMA C: col=lane&15, row=(lane>>4)*4+reg;
// A-frag: lane(lm,lg) = A[row=lm][k=lg*8+j].

#define DIMD 256
#define DIMH 64
#define DIMO 10
#define DT   320
#define NT   5        // 5 n-tiles of 16 = 80 cols (74 used)
#define TM   128      // rows per block: 8 waves x 16
#define BLOCK 512

typedef __attribute__((ext_vector_type(4))) float f32x4;
typedef __attribute__((ext_vector_type(8))) short bf16x8;

__device__ inline unsigned short f2bf(float f) {   // RNE, deterministic
    union { float f; unsigned u; } v; v.f = f;
    unsigned r = v.u + 0x7FFFu + ((v.u >> 16) & 1u);
    return (unsigned short)(r >> 16);
}
__device__ inline float sigm(float s) {
    return __builtin_amdgcn_rcpf(1.0f + __expf(-s));   // v_rcp_f32
}

__global__ __launch_bounds__(BLOCK, 2) void caspernet_kernel(
    const float* __restrict__ x,    // [B, 256]
    const float* __restrict__ Wh,   // [64, 320]
    const float* __restrict__ bh,   // [64]
    const float* __restrict__ Wo,   // [10, 320]
    const float* __restrict__ bo,   // [10]
    float* __restrict__ out,        // [B, 10]
    int B)
{
    __shared__ short sW[80 * DIMD];     // bf16 [n][k], swizzled;     40960B
    __shared__ short sUB[640 * 8];      // 10 slots x 64 lanes x 8;   10240B
    __shared__ float sT[8 * 320];       // per-wave 16x20 patches;    10240B
    __shared__ float sBias[80];         //                              320B
                                        // total ~60.3KB -> 2 blocks/CU

    const int tid = threadIdx.x;

    // ---- stage W1 = [Wh_x; Wo_x] as bf16, swizzled (short4 writes) ----
    for (int idx = tid; idx < 80 * 64; idx += BLOCK) {   // 80 rows x 64 float4
        const int n = idx >> 6, k0 = (idx & 63) * 4;
        float4 v = make_float4(0.f, 0.f, 0.f, 0.f);
        if (n < DIMH)      v = *reinterpret_cast<const float4*>(Wh + n * DT + k0);
        else if (n < 74)   v = *reinterpret_cast<const float4*>(Wo + (n - 64) * DT + k0);
        const int kz = k0 ^ ((n & 7) << 3);
        short4 sv;
        sv.x = (short)f2bf(v.x); sv.y = (short)f2bf(v.y);
        sv.z = (short)f2bf(v.z); sv.w = (short)f2bf(v.w);
        *reinterpret_cast<short4*>(sW + n * DIMD + kz) = sv;   // 8B aligned
    }
    // ---- build B-frag blob in-block ----
    for (int e = tid; e < 640; e += BLOCK) {
        const int p = e >> 6, l2 = e & 63;
        int g, t;
        if      (p < 4) { g = 0; t = p + 1; }
        else if (p < 7) { g = 1; t = p - 2; }      // p=4,5,6 -> t=2,3,4
        else if (p < 9) { g = 2; t = p - 4; }      // p=7,8   -> t=3,4
        else            { g = 3; t = 4;     }
        const int lm2 = l2 & 15, lg2 = l2 >> 4;
        const int col = t * 16 + lm2;
        short4 lo = {0, 0, 0, 0}, hi = {0, 0, 0, 0};
        if (lg2 < 2 && col < 74) {
            const float* src = (col < DIMH)
                ? (Wh + col * DT + DIMD + g * 16 + lg2 * 8)
                : (Wo + (col - DIMH) * DT + DIMD + g * 16 + lg2 * 8);
            const float4 a = *reinterpret_cast<const float4*>(src);
            const float4 b = *reinterpret_cast<const float4*>(src + 4);
            lo.x = (short)f2bf(a.x); lo.y = (short)f2bf(a.y);
            lo.z = (short)f2bf(a.z); lo.w = (short)f2bf(a.w);
            hi.x = (short)f2bf(b.x); hi.y = (short)f2bf(b.y);
            hi.z = (short)f2bf(b.z); hi.w = (short)f2bf(b.w);
        }
        *reinterpret_cast<short4*>(sUB + e * 8)     = lo;
        *reinterpret_cast<short4*>(sUB + e * 8 + 4) = hi;
    }
    if (tid < 80) sBias[tid] = (tid < 64) ? bh[tid] : ((tid < 74) ? bo[tid - 64] : 0.f);
    __syncthreads();                    // the ONLY block-wide barrier

    const int l  = tid & 63;
    const int w  = tid >> 6;            // wave 0..7 -> rows w*16..w*16+15
    const int lm = l & 15, lg = l >> 4;

    // ---- phase 1: one 16-row tile per wave ----
    const size_t rowA = (size_t)blockIdx.x * TM + w * 16 + lm;
    const float* xr = x + rowA * DIMD + lg * 8;

    f32x4 acc[NT];
    #pragma unroll
    for (int t = 0; t < NT; ++t) acc[t] = (f32x4){0.f, 0.f, 0.f, 0.f};

    #pragma unroll
    for (int ks = 0; ks < 8; ++ks) {
        const float4 xa = *reinterpret_cast<const float4*>(xr + ks * 32);
        const float4 xb = *reinterpret_cast<const float4*>(xr + ks * 32 + 4);
        bf16x8 af;
        af[0] = (short)f2bf(xa.x); af[1] = (short)f2bf(xa.y);
        af[2] = (short)f2bf(xa.z); af[3] = (short)f2bf(xa.w);
        af[4] = (short)f2bf(xb.x); af[5] = (short)f2bf(xb.y);
        af[6] = (short)f2bf(xb.z); af[7] = (short)f2bf(xb.w);
        #pragma unroll
        for (int t = 0; t < NT; ++t) {
            const int n = t * 16 + lm;
            const int kz = (lg * 8 + ks * 32) ^ ((n & 7) << 3);
            const bf16x8 bf = *reinterpret_cast<const bf16x8*>(sW + n * DIMD + kz);
            acc[t] = __builtin_amdgcn_mfma_f32_16x16x32_bf16(af, bf, acc[t], 0, 0, 0);
        }
    }
    #pragma unroll
    for (int t = 0; t < NT; ++t) {
        const float bt = sBias[t * 16 + lm];
        acc[t][0] += bt; acc[t][1] += bt; acc[t][2] += bt; acc[t][3] += bt;
    }

    // NO second barrier: each wave proceeds into its private patch.

    // ---- phase 2: blocked cascade on the per-wave patch ----
    float* tb = sT + w * 320;           // 16x20 f32, private to wave w
    #pragma unroll
    for (int g = 0; g < 4; ++g) {
        // 1) transpose tile g: C(col=lm, row=lg*4+r) -> tb[row*20+col]
        #pragma unroll
        for (int r = 0; r < 4; ++r)
            tb[(lg * 4 + r) * 20 + lm] = acc[g][r];
        // lane lm picks up its ROW (4 lg copies read same addr = broadcast)
        float s[16];
        #pragma unroll
        for (int q = 0; q < 4; ++q) {
            const f32x4 v = *reinterpret_cast<const f32x4*>(tb + lm * 20 + q * 4);
            s[q * 4 + 0] = v[0]; s[q * 4 + 1] = v[1];
            s[q * 4 + 2] = v[2]; s[q * 4 + 3] = v[3];
        }
        // 2) lane-local triangular solve; coefficients via wave-uniform
        //    s_loads directly from Wh
        const float* cg = Wh + (g * 16) * DT + DIMD + g * 16;  // c(k,m)=cg[k*DT+m]
        float h[16];
        h[0] = sigm(s[0]);
        #pragma unroll
        for (int k = 1; k < 16; ++k) {
            float a_ = s[k];
            #pragma unroll
            for (int m = 0; m < k; ++m)
                a_ = fmaf(cg[k * DT + m], h[m], a_);
            h[k] = sigm(a_);
        }
        // 3) A-frag from local h (lg selects k-chunk; lg>=2 are K-pad zeros)
        bf16x8 haf;
        #pragma unroll
        for (int j = 0; j < 8; ++j) {
            const float hv = (lg == 0) ? h[j] : ((lg == 1) ? h[8 + j] : 0.f);
            haf[j] = (short)f2bf(hv);
        }
        // 4) rank-16 MFMA update of all future tiles (incl. head tile 4)
        const int pbase = (g == 0) ? 0 : (g == 1) ? 4 : (g == 2) ? 7 : 9;
        #pragma unroll
        for (int t = g + 1; t < NT; ++t) {
            const bf16x8 bf = *reinterpret_cast<const bf16x8*>(
                sUB + (pbase + t - g - 1) * 512 + l * 8);
            acc[t] = __builtin_amdgcn_mfma_f32_16x16x32_bf16(haf, bf, acc[t], 0, 0, 0);
        }
    }

    // ---- store head tile (cols 64..73 = C-tile 4) ----
    if (lm < DIMO) {
        const size_t orow0 = (size_t)blockIdx.x * TM + w * 16 + lg * 4;
        #pragma unroll
        for (int r = 0; r < 4; ++r)
            out[(orow0 + r) * DIMO + lm] = acc[4][r];
    }
}

extern "C" void kernel_launch(void* const* d_in, const int* in_sizes, int n_in,
                              void* d_out, int out_size, void* d_ws, size_t ws_size,
                              hipStream_t stream) {
    const float* x  = (const float*)d_in[0];
    const float* Wh = (const float*)d_in[1];
    const float* bh = (const float*)d_in[2];
    const float* Wo = (const float*)d_in[3];
    const float* bo = (const float*)d_in[4];
    float* out = (float*)d_out;

    const int B = in_sizes[0] / DIMD;      // 131072
    const int grid = B / TM;               // 1024

    hipLaunchKernelGGL(caspernet_kernel, dim3(grid), dim3(BLOCK), 0, stream,
                       x, Wh, bh, Wo, bo, out, B);
}

// Round 22
// 47.162 us; speedup vs baseline: 1.0116x; 1.0116x over previous
//
#include <hip/hip_runtime.h>
#include <math.h>

// CasperNet R22: B=131072, D=256, H=64, O=10.
// R16-R21 plateau ~47us, no pipe >23%. Audit found a 4x redundancy kept
// since R16: all four lg-groups solve the SAME 16 rows (lane lm reads
// patch row lm regardless of lg) -> 75% of solve work wasted, and the
// solve's serial chain (~900cy/group) dominates per-wave latency.
// R22: 4 m-tiles per wave (64 rows, acc[4][5]=80 VGPR, R13-validated):
//  - per group g: transpose ALL 4 m-tiles into a per-wave 64x33 f32
//    patch (stride 33 -> every access pattern <=2-way banks = free);
//  - each of the 64 lanes solves its OWN row (zero redundancy): the
//    same serial chain now covers 4x the rows;
//  - h returns via patch cols 16..31 to feed per-m-tile A-frags;
//  - B-frags read once per t, shared by 4 MFMAs.
// Patches alias dead sW (33.8KB <= 40KB). BLOCK=256, TMB=256, grid=512.
// Per-row math ops and order identical -> absmax exactly 0.03125.
// Spill tripwire: WRITE_SIZE must stay ~5.1MB (VGPR cap 256 at (256,2)).
// Layout (verified R5): MFMA C: col=lane&15, row=(lane>>4)*4+reg;
// A-frag: lane(lm,lg) = A[row=lm][k=lg*8+j].

#define DIMD 256
#define DIMH 64
#define DIMO 10
#define DT   320
#define NT   5        // 5 n-tiles of 16 = 80 cols (74 used)
#define TMB  256      // rows per block: 4 waves x 64
#define BLOCK 256
#define PST  33       // patch row stride (f32): conflict-free transpose

typedef __attribute__((ext_vector_type(4))) float f32x4;
typedef __attribute__((ext_vector_type(8))) short bf16x8;

__device__ inline unsigned short f2bf(float f) {   // RNE, deterministic
    union { float f; unsigned u; } v; v.f = f;
    unsigned r = v.u + 0x7FFFu + ((v.u >> 16) & 1u);
    return (unsigned short)(r >> 16);
}
__device__ inline float sigm(float s) {
    return __builtin_amdgcn_rcpf(1.0f + __expf(-s));   // v_rcp_f32
}

__global__ __launch_bounds__(BLOCK, 2) void caspernet_kernel(
    const float* __restrict__ x,    // [B, 256]
    const float* __restrict__ Wh,   // [64, 320]
    const float* __restrict__ bh,   // [64]
    const float* __restrict__ Wo,   // [10, 320]
    const float* __restrict__ bo,   // [10]
    float* __restrict__ out,        // [B, 10]
    int B)
{
    __shared__ short sW[80 * DIMD];     // bf16 [n][k], swizzled;     40960B
                                        //   phase 2: 4 x (64x33 f32) patches
    __shared__ short sUB[640 * 8];      // 10 slots x 64 lanes x 8;   10240B
    __shared__ float sBias[80];         //                              320B
                                        // total ~51.5KB

    const int tid = threadIdx.x;

    // ---- stage W1 = [Wh_x; Wo_x] as bf16, swizzled (short4 writes) ----
    for (int idx = tid; idx < 80 * 64; idx += BLOCK) {   // 80 rows x 64 float4
        const int n = idx >> 6, k0 = (idx & 63) * 4;
        float4 v = make_float4(0.f, 0.f, 0.f, 0.f);
        if (n < DIMH)      v = *reinterpret_cast<const float4*>(Wh + n * DT + k0);
        else if (n < 74)   v = *reinterpret_cast<const float4*>(Wo + (n - 64) * DT + k0);
        const int kz = k0 ^ ((n & 7) << 3);
        short4 sv;
        sv.x = (short)f2bf(v.x); sv.y = (short)f2bf(v.y);
        sv.z = (short)f2bf(v.z); sv.w = (short)f2bf(v.w);
        *reinterpret_cast<short4*>(sW + n * DIMD + kz) = sv;   // 8B aligned
    }
    // ---- build B-frag blob in-block ----
    for (int e = tid; e < 640; e += BLOCK) {
        const int p = e >> 6, l2 = e & 63;
        int g, t;
        if      (p < 4) { g = 0; t = p + 1; }
        else if (p < 7) { g = 1; t = p - 2; }      // p=4,5,6 -> t=2,3,4
        else if (p < 9) { g = 2; t = p - 4; }      // p=7,8   -> t=3,4
        else            { g = 3; t = 4;     }
        const int lm2 = l2 & 15, lg2 = l2 >> 4;
        const int col = t * 16 + lm2;
        short4 lo = {0, 0, 0, 0}, hi = {0, 0, 0, 0};
        if (lg2 < 2 && col < 74) {
            const float* src = (col < DIMH)
                ? (Wh + col * DT + DIMD + g * 16 + lg2 * 8)
                : (Wo + (col - DIMH) * DT + DIMD + g * 16 + lg2 * 8);
            const float4 a = *reinterpret_cast<const float4*>(src);
            const float4 b = *reinterpret_cast<const float4*>(src + 4);
            lo.x = (short)f2bf(a.x); lo.y = (short)f2bf(a.y);
            lo.z = (short)f2bf(a.z); lo.w = (short)f2bf(a.w);
            hi.x = (short)f2bf(b.x); hi.y = (short)f2bf(b.y);
            hi.z = (short)f2bf(b.z); hi.w = (short)f2bf(b.w);
        }
        *reinterpret_cast<short4*>(sUB + e * 8)     = lo;
        *reinterpret_cast<short4*>(sUB + e * 8 + 4) = hi;
    }
    if (tid < 80) sBias[tid] = (tid < 64) ? bh[tid] : ((tid < 74) ? bo[tid - 64] : 0.f);
    __syncthreads();

    const int l  = tid & 63;
    const int w  = tid >> 6;            // wave 0..3 -> rows w*64 .. w*64+63
    const int lm = l & 15, lg = l >> 4;
    const size_t rowbase = (size_t)blockIdx.x * TMB + w * 64;

    // ---- phase 1: 4 m-tiles (64 rows) per wave ----
    const float* xr = x + (rowbase + lm) * DIMD + lg * 8;

    f32x4 acc[4][NT];                   // 80 VGPRs
    #pragma unroll
    for (int mt = 0; mt < 4; ++mt)
        #pragma unroll
        for (int t = 0; t < NT; ++t) acc[mt][t] = (f32x4){0.f, 0.f, 0.f, 0.f};

    #pragma unroll 1                    // bound the load window (R7/R13 lesson)
    for (int ks = 0; ks < 8; ++ks) {
        bf16x8 af[4];
        #pragma unroll
        for (int mt = 0; mt < 4; ++mt) {
            const float4 xa = *reinterpret_cast<const float4*>(xr + mt * 16 * DIMD + ks * 32);
            const float4 xb = *reinterpret_cast<const float4*>(xr + mt * 16 * DIMD + ks * 32 + 4);
            af[mt][0] = (short)f2bf(xa.x); af[mt][1] = (short)f2bf(xa.y);
            af[mt][2] = (short)f2bf(xa.z); af[mt][3] = (short)f2bf(xa.w);
            af[mt][4] = (short)f2bf(xb.x); af[mt][5] = (short)f2bf(xb.y);
            af[mt][6] = (short)f2bf(xb.z); af[mt][7] = (short)f2bf(xb.w);
        }
        #pragma unroll
        for (int t = 0; t < NT; ++t) {
            const int n = t * 16 + lm;
            const int kz = (lg * 8 + ks * 32) ^ ((n & 7) << 3);
            const bf16x8 bf = *reinterpret_cast<const bf16x8*>(sW + n * DIMD + kz);
            #pragma unroll
            for (int mt = 0; mt < 4; ++mt)
                acc[mt][t] = __builtin_amdgcn_mfma_f32_16x16x32_bf16(af[mt], bf, acc[mt][t], 0, 0, 0);
        }
    }
    #pragma unroll
    for (int t = 0; t < NT; ++t) {
        const float bt = sBias[t * 16 + lm];
        #pragma unroll
        for (int mt = 0; mt < 4; ++mt) {
            acc[mt][t][0] += bt; acc[mt][t][1] += bt;
            acc[mt][t][2] += bt; acc[mt][t][3] += bt;
        }
    }

    __syncthreads();                    // all waves done reading sW -> alias

    // ---- phase 2: blocked cascade, 64 distinct rows per wave ----
    float* pb = reinterpret_cast<float*>(sW) + w * (64 * PST);  // 64x33 f32
    #pragma unroll
    for (int g = 0; g < 4; ++g) {
        // 1) transpose tile g of all 4 m-tiles into patch rows
        #pragma unroll
        for (int mt = 0; mt < 4; ++mt)
            #pragma unroll
            for (int r = 0; r < 4; ++r)
                pb[(mt * 16 + lg * 4 + r) * PST + lm] = acc[mt][g][r];
        // 2) lane l solves its OWN row l (cols 0..15); coefficients via
        //    wave-uniform s_loads directly from Wh
        float s[16];
        #pragma unroll
        for (int q = 0; q < 4; ++q) {
            const f32x4 v = *reinterpret_cast<const f32x4*>(pb + l * PST + q * 4);
            s[q * 4 + 0] = v[0]; s[q * 4 + 1] = v[1];
            s[q * 4 + 2] = v[2]; s[q * 4 + 3] = v[3];
        }
        const float* cg = Wh + (g * 16) * DT + DIMD + g * 16;  // c(k,m)=cg[k*DT+m]
        float h[16];
        h[0] = sigm(s[0]);
        #pragma unroll
        for (int k = 1; k < 16; ++k) {
            float a_ = s[k];
            #pragma unroll
            for (int m = 0; m < k; ++m)
                a_ = fmaf(cg[k * DT + m], h[m], a_);
            h[k] = sigm(a_);
        }
        // 3) write h to patch cols 16..31 (f32x4, 2-way banks)
        #pragma unroll
        for (int q = 0; q < 4; ++q) {
            f32x4 hv = { h[q * 4 + 0], h[q * 4 + 1], h[q * 4 + 2], h[q * 4 + 3] };
            *reinterpret_cast<f32x4*>(pb + l * PST + 16 + q * 4) = hv;
        }
        // 4) per-m-tile A-frags from patch; rank-16 MFMA updates.
        bf16x8 haf[4];
        #pragma unroll
        for (int mt = 0; mt < 4; ++mt) {
            if (lg < 2) {
                const float* hp = pb + (mt * 16 + lm) * PST + 16 + lg * 8;
                const f32x4 a = *reinterpret_cast<const f32x4*>(hp);
                const f32x4 b = *reinterpret_cast<const f32x4*>(hp + 4);
                haf[mt][0] = (short)f2bf(a[0]); haf[mt][1] = (short)f2bf(a[1]);
                haf[mt][2] = (short)f2bf(a[2]); haf[mt][3] = (short)f2bf(a[3]);
                haf[mt][4] = (short)f2bf(b[0]); haf[mt][5] = (short)f2bf(b[1]);
                haf[mt][6] = (short)f2bf(b[2]); haf[mt][7] = (short)f2bf(b[3]);
            } else {
                #pragma unroll
                for (int j = 0; j < 8; ++j) haf[mt][j] = 0;   // K-pad zeros
            }
        }
        const int pbase = (g == 0) ? 0 : (g == 1) ? 4 : (g == 2) ? 7 : 9;
        #pragma unroll
        for (int t = g + 1; t < NT; ++t) {
            const bf16x8 bf = *reinterpret_cast<const bf16x8*>(
                sUB + (pbase + t - g - 1) * 512 + l * 8);
            #pragma unroll
            for (int mt = 0; mt < 4; ++mt)
                acc[mt][t] = __builtin_amdgcn_mfma_f32_16x16x32_bf16(haf[mt], bf, acc[mt][t], 0, 0, 0);
        }
    }

    // ---- store head tiles (cols 64..73 = C-tile 4) ----
    if (lm < DIMO) {
        #pragma unroll
        for (int mt = 0; mt < 4; ++mt) {
            const size_t orow0 = rowbase + mt * 16 + lg * 4;
            #pragma unroll
            for (int r = 0; r < 4; ++r)
                out[(orow0 + r) * DIMO + lm] = acc[mt][4][r];
        }
    }
}

extern "C" void kernel_launch(void* const* d_in, const int* in_sizes, int n_in,
                              void* d_out, int out_size, void* d_ws, size_t ws_size,
                              hipStream_t stream) {
    const float* x  = (const float*)d_in[0];
    const float* Wh = (const float*)d_in[1];
    const float* bh = (const float*)d_in[2];
    const float* Wo = (const float*)d_in[3];
    const float* bo = (const float*)d_in[4];
    float* out = (float*)d_out;

    const int B = in_sizes[0] / DIMD;      // 131072
    const int grid = B / TMB;              // 512

    hipLaunchKernelGGL(caspernet_kernel, dim3(grid), dim3(BLOCK), 0, stream,
                       x, Wh, bh, Wo, bo, out, B);
}